// Round 7
// baseline (572.303 us; speedup 1.0000x reference)
//
#include <hip/hip_runtime.h>
#include <math.h>

// Shapes: B=4, N=16384 (NROW=65536 rows), C=64, K=1024, D1=128, D2=64
#define NROW   65536
#define INV_BN (1.f/65536.f)
#define EPSF   1e-5f

// ------------------------------------------------------------------ k_prep (1024 thr: 16 waves/CU)
// per (b,c): g[bc]=mean_k img; dv[bc]=(1/K)sum_k b3[k]*img; MT[b][j][c]=(1/K)sum_k W3[k][j]*img[bc][k]
__global__ __launch_bounds__(1024) void k_prep(const float* __restrict__ img,
        const float* __restrict__ W3, const float* __restrict__ b3,
        float* __restrict__ g, float* __restrict__ MT, float* __restrict__ dv) {
    __shared__ float imgs[1024];
    __shared__ float mr[16][64];
    __shared__ float red[1024], red2[1024];
    const int bc = blockIdx.x;           // 256 blocks
    const int t = threadIdx.x;
    const int b = bc >> 6, c = bc & 63;
    imgs[t] = img[bc*1024 + t];
    red[t] = b3[t];                      // stash b3 to overlap
    __syncthreads();
    const int j = t & 63, kk = t >> 6;   // kk 0..15, k-range 64
    float a = 0.f;
    #pragma unroll
    for (int k = kk*64; k < kk*64 + 64; ++k) a += imgs[k] * W3[k*64 + j];
    mr[kk][j] = a;
    float iv = imgs[t];
    float dvp = red[t] * iv;
    __syncthreads();
    red[t] = dvp; red2[t] = iv;
    __syncthreads();
    if (t < 64) {
        float m = 0.f;
        #pragma unroll
        for (int q = 0; q < 16; ++q) m += mr[q][t];
        MT[(b*64 + t)*64 + c] = m * (1.f/1024.f);
    }
    for (int w = 512; w > 0; w >>= 1) {
        if (t < w) { red[t] += red[t+w]; red2[t] += red2[t+w]; }
        __syncthreads();
    }
    if (t == 0) { dv[bc] = red[0]*(1.f/1024.f); g[bc] = red2[0]*(1.f/1024.f); }
}

// ------------------------------------------------------------------ k_wt: weight transposes + c1
__global__ __launch_bounds__(512) void k_wt(const float* __restrict__ W1,
        const float* __restrict__ W2, const float* __restrict__ b1,
        const float* __restrict__ g, float* __restrict__ W1hT,
        float* __restrict__ W2T, float* __restrict__ c1) {
    const int t = threadIdx.x;
    for (int i = t; i < 8192; i += 512) {           // W1hT[c][o] = W1[o][64+c]
        int c = i >> 7, o = i & 127;
        W1hT[i] = W1[o*128 + 64 + c];
    }
    for (int i = t; i < 8192; i += 512) {           // W2T[o][j] = W2[j][o]
        int o = i >> 6, jj = i & 63;
        W2T[i] = W2[jj*128 + o];
    }
    const int b = t >> 7, o = t & 127;              // c1[b][o]
    float s = b1[o];
    #pragma unroll 8
    for (int c = 0; c < 64; ++c) s += g[b*64 + c] * W1[o*128 + c];
    c1[t] = s;
}

// ------------------------------------------------------------------ k_mom: block-local partial Gram + col-sums
// 1024 blocks x 64 rows; per-thread 4x4 tile: 2 ds_read_b128 + 16 FMA per row
__global__ __launch_bounds__(256) void k_mom(const float* __restrict__ lidar,
        float* __restrict__ Gp, float* __restrict__ Sp) {
    __shared__ __align__(16) float LR[64*68];        // [r][c], pad 68
    const int t = threadIdx.x;
    const int blk = blockIdx.x;                      // 1024
    {   // contiguous 16 KB stage, float4
        const float* src = lidar + (size_t)blk * 4096;
        for (int i4 = t; i4 < 1024; i4 += 256) {
            int r = i4 >> 4, c4 = (i4 & 15) * 4;
            *(float4*)&LR[r*68 + c4] = *(const float4*)&src[i4*4];
        }
    }
    __syncthreads();
    const int ca = (t >> 4) * 4;                     // row of G (coalesced partial writes)
    const int cb = (t & 15) * 4;                     // col of G
    float acc[4][4] = {};
    float s4[4] = {};
    #pragma unroll 4
    for (int r = 0; r < 64; ++r) {
        float a[4], bb[4];
        *(float4*)a  = *(const float4*)&LR[r*68 + ca];   // 16-way broadcast groups
        *(float4*)bb = *(const float4*)&LR[r*68 + cb];   // 16 chunks x 4-way
        #pragma unroll
        for (int i = 0; i < 4; ++i)
            #pragma unroll
            for (int jj = 0; jj < 4; ++jj)
                acc[i][jj] += a[i] * bb[jj];
        if ((t & 15) == 0) {
            #pragma unroll
            for (int i = 0; i < 4; ++i) s4[i] += a[i];
        }
    }
    float* gp = Gp + (size_t)blk * 4096;
    #pragma unroll
    for (int i = 0; i < 4; ++i)
        *(float4*)&gp[(ca + i)*64 + cb] = *(float4*)acc[i];   // lanes cover contiguous rows
    if ((t & 15) == 0)
        *(float4*)&Sp[blk*64 + ca] = *(float4*)s4;
}

// ------------------------------------------------------------------ k_mred: reduce partials -> G[4][64][64], S[4][64]
__global__ __launch_bounds__(256) void k_mred(const float* __restrict__ Gp,
        const float* __restrict__ Sp, float* __restrict__ G, float* __restrict__ S) {
    const int t = threadIdx.x;
    if (blockIdx.x < 64) {
        const int idx = blockIdx.x * 256 + t;        // 0..16383
        const int b = idx >> 12, i = idx & 4095;
        const float* p = Gp + (size_t)(b*256)*4096 + i;
        float s = 0.f;
        #pragma unroll 8
        for (int q = 0; q < 256; ++q) s += p[(size_t)q*4096];
        G[idx] = s;
    } else {
        const int b = t >> 6, c = t & 63;            // 256 outputs
        const float* p = Sp + (b*256)*64 + c;
        float s = 0.f;
        #pragma unroll 8
        for (int q = 0; q < 256; ++q) s += p[q*64];
        S[t] = s;
    }
}

// ------------------------------------------------------------------ k_stats1: analytic BN1 stats -> sc1
// SumY = sum_b (w.S_b + N c1); SumY2 = sum_b (w^T G_b w + 2 c1 (w.S_b) + N c1^2)
__global__ __launch_bounds__(256) void k_stats1(const float* __restrict__ G,
        const float* __restrict__ S, const float* __restrict__ c1,
        const float* __restrict__ W1hT, const float* __restrict__ g1,
        const float* __restrict__ be1, float* __restrict__ sc) {
    __shared__ float wl[64];
    __shared__ float pb1[4], pb2[4];
    const int o = blockIdx.x;            // 128 blocks
    const int t = threadIdx.x;
    if (t < 64) wl[t] = W1hT[t*128 + o];
    __syncthreads();
    const int b = t >> 6, ca = t & 63;   // wave b
    const float* Gb = G + b*4096 + ca*64;
    float r = 0.f;
    #pragma unroll 8
    for (int cb = 0; cb < 64; ++cb) r += Gb[cb] * wl[cb];
    float p2 = wl[ca] * r;
    float p1 = wl[ca] * S[b*64 + ca];
    #pragma unroll
    for (int m = 32; m > 0; m >>= 1) {
        p1 += __shfl_xor(p1, m);
        p2 += __shfl_xor(p2, m);
    }
    if (ca == 0) { pb1[b] = p1; pb2[b] = p2; }
    __syncthreads();
    if (t == 0) {
        float sy = 0.f, sy2 = 0.f;
        #pragma unroll
        for (int bb = 0; bb < 4; ++bb) {
            float cc = c1[bb*128 + o];
            sy  += pb1[bb] + 16384.f*cc;
            sy2 += pb2[bb] + 2.f*cc*pb1[bb] + 16384.f*cc*cc;
        }
        float mu = sy * INV_BN;
        float var = sy2 * INV_BN - mu*mu;
        float s = g1[o] * rsqrtf(var + EPSF);
        sc[o] = s; sc[128 + o] = be1[o] - mu*s;
    }
}

// ------------------------------------------------------------------ k_fused12: gemm1+bn1+relu+gemm2 (+fused BN2 stats)
// 1024 blocks x 64 rows, 256 threads. LDS phases: {LT,W1s} -> {Z,W2s} (aliased, 66 KB)
__global__ __launch_bounds__(256) void k_fused12(const float* __restrict__ lidar,
        const float* __restrict__ W1hT, const float* __restrict__ W2T,
        const float* __restrict__ c1, const float* __restrict__ sc,
        const float* __restrict__ b2, float* __restrict__ y2T,
        float* __restrict__ st2) {
    __shared__ __align__(16) float buf[16512];
    float* LT  = buf;          // [c][row] 64x65 (phase 1)
    float* W1s = buf + 4160;   // [c][o]   64x128 (phase 1)
    float* Z   = buf;          // [o][row] 128x65 (phase 2)
    float* W2s = buf + 8320;   // [o][j]   128x64 (phase 2)
    const int t = threadIdx.x;
    const int base = blockIdx.x * 64;
    const int b = blockIdx.x >> 8;
    const int lane = t & 63;
    const int w = t >> 6;
    // stage lidar tile transposed + W1h
    for (int i = t; i < 4096; i += 256) {
        int r = i >> 6, c = i & 63;
        LT[c*65 + r] = lidar[(size_t)(base + r)*64 + c];   // coalesced read
    }
    for (int i = t; i < 2048; i += 256)
        *(float4*)&W1s[i*4] = *(const float4*)&W1hT[i*4];
    __syncthreads();
    // gemm1: lane=row, wave owns 32 o-chans
    const int wo = w * 32;
    float acc1[32] = {};
    #pragma unroll 2
    for (int c = 0; c < 64; ++c) {
        float a = LT[c*65 + lane];
        float wv[32];
        #pragma unroll
        for (int q = 0; q < 8; ++q)
            *(float4*)&wv[q*4] = *(const float4*)&W1s[c*128 + wo + q*4];  // uniform b128
        #pragma unroll
        for (int i = 0; i < 32; ++i) acc1[i] += a * wv[i];
    }
    __syncthreads();                     // LT/W1s dead
    // bn1+relu -> Z; stage W2s
    #pragma unroll
    for (int i = 0; i < 32; ++i) {
        int o = wo + i;
        float v = fmaf(acc1[i] + c1[b*128 + o], sc[o], sc[128 + o]);
        Z[o*65 + lane] = fmaxf(v, 0.f);
    }
    for (int i = t; i < 2048; i += 256)
        *(float4*)&W2s[i*4] = *(const float4*)&W2T[i*4];
    __syncthreads();
    // gemm2: lane=row, wave owns 16 j
    const int wj = w * 16;
    float acc2[16] = {};
    #pragma unroll 2
    for (int o = 0; o < 128; ++o) {
        float zv = Z[o*65 + lane];
        float wv[16];
        #pragma unroll
        for (int q = 0; q < 4; ++q)
            *(float4*)&wv[q*4] = *(const float4*)&W2s[o*64 + wj + q*4];
        #pragma unroll
        for (int i = 0; i < 16; ++i) acc2[i] += zv * wv[i];
    }
    float s16[16], q16[16];
    #pragma unroll
    for (int i = 0; i < 16; ++i) {
        float v = acc2[i] + b2[wj + i];
        y2T[(size_t)(wj + i)*NROW + base + lane] = v;
        s16[i] = v; q16[i] = v*v;
    }
    // fused BN2 stats: wave-reduce over the 64 rows (lanes), then atomics
    #pragma unroll
    for (int m = 1; m < 64; m <<= 1) {
        #pragma unroll
        for (int i = 0; i < 16; ++i) {
            s16[i] += __shfl_xor(s16[i], m);
            q16[i] += __shfl_xor(q16[i], m);
        }
    }
    if (lane == 0) {
        #pragma unroll
        for (int i = 0; i < 16; ++i) {
            atomicAdd(&st2[wj + i], s16[i]);
            atomicAdd(&st2[64 + wj + i], q16[i]);
        }
    }
}

__global__ void k_fin2(const float* __restrict__ st2, const float* __restrict__ g2,
                       const float* __restrict__ be2, float* __restrict__ sc2) {
    const int o = threadIdx.x;  // 64
    float mu = st2[o] * INV_BN;
    float var = st2[64 + o] * INV_BN - mu*mu;
    float s = g2[o] * rsqrtf(var + EPSF);
    sc2[o] = s; sc2[64 + o] = be2[o] - mu*s;
}

// ------------------------------------------------------------------ GEMM3: lane=row, wave=16 c, M in LDS; LDS out-transpose
// out[row][c] = sum_j relu(bn2(y2T[j][row]))*MT[b][j][c] + dv[b][c]
__global__ __launch_bounds__(256) void k_gemm3(const float* __restrict__ y2T,
        const float* __restrict__ MT, const float* __restrict__ dv,
        const float* __restrict__ sc2, float* __restrict__ out) {
    __shared__ __align__(16) float Ml[64*64];        // 16 KB
    __shared__ float Ot[64*65];                      // 16.6 KB
    const int t = threadIdx.x;
    const int base = blockIdx.x * 64;                // 1024 blocks
    const int b = blockIdx.x >> 8;
    for (int i = t; i < 1024; i += 256)
        *(float4*)&Ml[i*4] = *(const float4*)&MT[b*4096 + i*4];
    __syncthreads();
    const int lane = t & 63;
    const int wc = (t >> 6) * 16;
    const float* ap = y2T + base + lane;
    float acc[16] = {};
    #pragma unroll 4
    for (int j = 0; j < 64; ++j) {
        float v = ap[(size_t)j*NROW];
        v = fmaxf(fmaf(v, sc2[j], sc2[64 + j]), 0.f); // bn2 + relu
        float wv[16];
        #pragma unroll
        for (int q = 0; q < 4; ++q)
            *(float4*)&wv[q*4] = *(const float4*)&Ml[j*64 + wc + q*4];
        #pragma unroll
        for (int ci = 0; ci < 16; ++ci) acc[ci] += v * wv[ci];
    }
    #pragma unroll
    for (int ci = 0; ci < 16; ++ci)
        Ot[(wc + ci)*65 + lane] = acc[ci] + dv[b*64 + wc + ci];
    __syncthreads();
    for (int i = t; i < 4096; i += 256) {            // coalesced row-major store
        int r = i >> 6, c = i & 63;
        out[(base + r)*64 + c] = Ot[c*65 + r];
    }
}

// ------------------------------------------------------------------
extern "C" void kernel_launch(void* const* d_in, const int* in_sizes, int n_in,
                              void* d_out, int out_size, void* d_ws, size_t ws_size,
                              hipStream_t stream) {
    const float* lidar = (const float*)d_in[0];
    const float* img   = (const float*)d_in[1];
    const float* W1  = (const float*)d_in[2];
    const float* b1  = (const float*)d_in[3];
    const float* g1  = (const float*)d_in[4];
    const float* be1 = (const float*)d_in[5];
    const float* W2  = (const float*)d_in[6];
    const float* b2  = (const float*)d_in[7];
    const float* g2  = (const float*)d_in[8];
    const float* be2 = (const float*)d_in[9];
    const float* W3  = (const float*)d_in[10];
    const float* b3  = (const float*)d_in[11];

    float* ws   = (float*)d_ws;
    float* y2T  = ws;                    // 64*65536
    float* g    = y2T + 64*NROW;         // 256
    float* c1   = g    + 256;            // 512
    float* MT   = c1   + 512;            // 16384
    float* dv   = MT   + 16384;          // 256
    float* W1hT = dv   + 256;            // 8192
    float* W2T  = W1hT + 8192;           // 8192
    float* sc1  = W2T  + 8192;           // 256
    float* sc2  = sc1  + 256;            // 128
    float* G    = sc2  + 128;            // 16384
    float* S    = G    + 16384;          // 256
    float* st2  = S    + 256;            // 128   -- zeroed
    float* Gp   = st2  + 128;            // 1024*4096
    float* Sp   = Gp   + 1024*4096;      // 1024*64

    hipMemsetAsync(st2, 0, 128 * sizeof(float), stream);

    k_prep   <<<256,  1024, 0, stream>>>(img, W3, b3, g, MT, dv);
    k_wt     <<<1,    512,  0, stream>>>(W1, W2, b1, g, W1hT, W2T, c1);
    k_mom    <<<1024, 256,  0, stream>>>(lidar, Gp, Sp);
    k_mred   <<<65,   256,  0, stream>>>(Gp, Sp, G, S);
    k_stats1 <<<128,  256,  0, stream>>>(G, S, c1, W1hT, g1, be1, sc1);
    k_fused12<<<1024, 256,  0, stream>>>(lidar, W1hT, W2T, c1, sc1, b2, y2T, st2);
    k_fin2   <<<1,    64,   0, stream>>>(st2, g2, be2, sc2);
    k_gemm3  <<<1024, 256,  0, stream>>>(y2T, MT, dv, sc2, (float*)d_out);
}

// Round 8
// 213.431 us; speedup vs baseline: 2.6814x; 2.6814x over previous
//
#include <hip/hip_runtime.h>
#include <math.h>

// Shapes: B=4, N=16384 (NROW=65536 rows), C=64, K=1024, D1=128, D2=64
#define NROW   65536
#define INV_BN (1.f/65536.f)
#define EPSF   1e-5f

// ------------------------------------------------------------------ k_prep (1024 thr: 16 waves/CU)
// per (b,c): g[bc]=mean_k img; dv[bc]=(1/K)sum_k b3[k]*img; MT[b][j][c]=(1/K)sum_k W3[k][j]*img[bc][k]
__global__ __launch_bounds__(1024) void k_prep(const float* __restrict__ img,
        const float* __restrict__ W3, const float* __restrict__ b3,
        float* __restrict__ g, float* __restrict__ MT, float* __restrict__ dv) {
    __shared__ float imgs[1024];
    __shared__ float mr[16][64];
    __shared__ float red[1024], red2[1024];
    const int bc = blockIdx.x;           // 256 blocks
    const int t = threadIdx.x;
    const int b = bc >> 6, c = bc & 63;
    imgs[t] = img[bc*1024 + t];
    red[t] = b3[t];                      // stash b3 to overlap
    __syncthreads();
    const int j = t & 63, kk = t >> 6;   // kk 0..15, k-range 64
    float a = 0.f;
    #pragma unroll
    for (int k = kk*64; k < kk*64 + 64; ++k) a += imgs[k] * W3[k*64 + j];
    mr[kk][j] = a;
    float iv = imgs[t];
    float dvp = red[t] * iv;
    __syncthreads();
    red[t] = dvp; red2[t] = iv;
    __syncthreads();
    if (t < 64) {
        float m = 0.f;
        #pragma unroll
        for (int q = 0; q < 16; ++q) m += mr[q][t];
        MT[(b*64 + t)*64 + c] = m * (1.f/1024.f);
    }
    for (int w = 512; w > 0; w >>= 1) {
        if (t < w) { red[t] += red[t+w]; red2[t] += red2[t+w]; }
        __syncthreads();
    }
    if (t == 0) { dv[bc] = red[0]*(1.f/1024.f); g[bc] = red2[0]*(1.f/1024.f); }
}

// ------------------------------------------------------------------ k_wt: weight transposes + c1
__global__ __launch_bounds__(512) void k_wt(const float* __restrict__ W1,
        const float* __restrict__ W2, const float* __restrict__ b1,
        const float* __restrict__ g, float* __restrict__ W1hT,
        float* __restrict__ W2T, float* __restrict__ c1) {
    const int t = threadIdx.x;
    for (int i = t; i < 8192; i += 512) {           // W1hT[c][o] = W1[o][64+c]
        int c = i >> 7, o = i & 127;
        W1hT[i] = W1[o*128 + 64 + c];
    }
    for (int i = t; i < 8192; i += 512) {           // W2T[o][j] = W2[j][o]
        int o = i >> 6, jj = i & 63;
        W2T[i] = W2[jj*128 + o];
    }
    const int b = t >> 7, o = t & 127;              // c1[b][o]
    float s = b1[o];
    #pragma unroll 8
    for (int c = 0; c < 64; ++c) s += g[b*64 + c] * W1[o*128 + c];
    c1[t] = s;
}

// ------------------------------------------------------------------ k_mom: block-local partial Gram + col-sums
// 1024 blocks x 64 rows; per-thread 4x4 tile: 2 ds_read_b128 + 16 FMA per row
__global__ __launch_bounds__(256) void k_mom(const float* __restrict__ lidar,
        float* __restrict__ Gp, float* __restrict__ Sp) {
    __shared__ __align__(16) float LR[64*68];        // [r][c], pad 68
    const int t = threadIdx.x;
    const int blk = blockIdx.x;                      // 1024
    {   // contiguous 16 KB stage, float4
        const float* src = lidar + (size_t)blk * 4096;
        for (int i4 = t; i4 < 1024; i4 += 256) {
            int r = i4 >> 4, c4 = (i4 & 15) * 4;
            *(float4*)&LR[r*68 + c4] = *(const float4*)&src[i4*4];
        }
    }
    __syncthreads();
    const int ca = (t >> 4) * 4;                     // row of G (coalesced partial writes)
    const int cb = (t & 15) * 4;                     // col of G
    float acc[4][4] = {};
    float s4[4] = {};
    #pragma unroll 4
    for (int r = 0; r < 64; ++r) {
        float a[4], bb[4];
        *(float4*)a  = *(const float4*)&LR[r*68 + ca];   // 16-way broadcast groups
        *(float4*)bb = *(const float4*)&LR[r*68 + cb];   // 16 chunks x 4-way
        #pragma unroll
        for (int i = 0; i < 4; ++i)
            #pragma unroll
            for (int jj = 0; jj < 4; ++jj)
                acc[i][jj] += a[i] * bb[jj];
        if ((t & 15) == 0) {
            #pragma unroll
            for (int i = 0; i < 4; ++i) s4[i] += a[i];
        }
    }
    float* gp = Gp + (size_t)blk * 4096;
    #pragma unroll
    for (int i = 0; i < 4; ++i)
        *(float4*)&gp[(ca + i)*64 + cb] = *(float4*)acc[i];   // lanes cover contiguous rows
    if ((t & 15) == 0)
        *(float4*)&Sp[blk*64 + ca] = *(float4*)s4;
}

// ------------------------------------------------------------------ k_mred: reduce partials -> G[4][64][64], S[4][64]
__global__ __launch_bounds__(256) void k_mred(const float* __restrict__ Gp,
        const float* __restrict__ Sp, float* __restrict__ G, float* __restrict__ S) {
    const int t = threadIdx.x;
    if (blockIdx.x < 64) {
        const int idx = blockIdx.x * 256 + t;        // 0..16383
        const int b = idx >> 12, i = idx & 4095;
        const float* p = Gp + (size_t)(b*256)*4096 + i;
        float s = 0.f;
        #pragma unroll 8
        for (int q = 0; q < 256; ++q) s += p[(size_t)q*4096];
        G[idx] = s;
    } else {
        const int b = t >> 6, c = t & 63;            // 256 outputs
        const float* p = Sp + (b*256)*64 + c;
        float s = 0.f;
        #pragma unroll 8
        for (int q = 0; q < 256; ++q) s += p[q*64];
        S[t] = s;
    }
}

// ------------------------------------------------------------------ k_stats1: analytic BN1 stats -> sc1
// SumY = sum_b (w.S_b + N c1); SumY2 = sum_b (w^T G_b w + 2 c1 (w.S_b) + N c1^2)
__global__ __launch_bounds__(256) void k_stats1(const float* __restrict__ G,
        const float* __restrict__ S, const float* __restrict__ c1,
        const float* __restrict__ W1hT, const float* __restrict__ g1,
        const float* __restrict__ be1, float* __restrict__ sc) {
    __shared__ float wl[64];
    __shared__ float pb1[4], pb2[4];
    const int o = blockIdx.x;            // 128 blocks
    const int t = threadIdx.x;
    if (t < 64) wl[t] = W1hT[t*128 + o];
    __syncthreads();
    const int b = t >> 6, ca = t & 63;   // wave b
    const float* Gb = G + b*4096 + ca*64;
    float r = 0.f;
    #pragma unroll 8
    for (int cb = 0; cb < 64; ++cb) r += Gb[cb] * wl[cb];
    float p2 = wl[ca] * r;
    float p1 = wl[ca] * S[b*64 + ca];
    #pragma unroll
    for (int m = 32; m > 0; m >>= 1) {
        p1 += __shfl_xor(p1, m);
        p2 += __shfl_xor(p2, m);
    }
    if (ca == 0) { pb1[b] = p1; pb2[b] = p2; }
    __syncthreads();
    if (t == 0) {
        float sy = 0.f, sy2 = 0.f;
        #pragma unroll
        for (int bb = 0; bb < 4; ++bb) {
            float cc = c1[bb*128 + o];
            sy  += pb1[bb] + 16384.f*cc;
            sy2 += pb2[bb] + 2.f*cc*pb1[bb] + 16384.f*cc*cc;
        }
        float mu = sy * INV_BN;
        float var = sy2 * INV_BN - mu*mu;
        float s = g1[o] * rsqrtf(var + EPSF);
        sc[o] = s; sc[128 + o] = be1[o] - mu*s;
    }
}

// ------------------------------------------------------------------ k_fused12: gemm1+bn1+relu+gemm2 (+fused BN2 stats)
// 1024 blocks x 64 rows, 256 threads. LDS phases: {LT,W1s} -> {Z,W2s} -> {SR,QR} (aliased, 66 KB)
__global__ __launch_bounds__(256) void k_fused12(const float* __restrict__ lidar,
        const float* __restrict__ W1hT, const float* __restrict__ W2T,
        const float* __restrict__ c1, const float* __restrict__ sc,
        const float* __restrict__ b2, float* __restrict__ y2T,
        float* __restrict__ st2) {
    __shared__ __align__(16) float buf[16512];
    float* LT  = buf;          // [c][row] 64x65 (phase 1)
    float* W1s = buf + 4160;   // [c][o]   64x128 (phase 1)
    float* Z   = buf;          // [o][row] 128x65 (phase 2)
    float* W2s = buf + 8320;   // [o][j]   128x64 (phase 2)
    float* SR  = buf;          // [64ch][68] (phase 3, padded)
    float* QR  = buf + 4352;   // [64ch][68] (phase 3)
    const int t = threadIdx.x;
    const int base = blockIdx.x * 64;
    const int b = blockIdx.x >> 8;
    const int lane = t & 63;
    const int w = t >> 6;
    // stage lidar tile transposed + W1h
    for (int i = t; i < 4096; i += 256) {
        int r = i >> 6, c = i & 63;
        LT[c*65 + r] = lidar[(size_t)(base + r)*64 + c];   // coalesced read
    }
    for (int i = t; i < 2048; i += 256)
        *(float4*)&W1s[i*4] = *(const float4*)&W1hT[i*4];
    __syncthreads();
    // gemm1: lane=row, wave owns 32 o-chans
    const int wo = w * 32;
    float acc1[32] = {};
    #pragma unroll 2
    for (int c = 0; c < 64; ++c) {
        float a = LT[c*65 + lane];
        float wv[32];
        #pragma unroll
        for (int q = 0; q < 8; ++q)
            *(float4*)&wv[q*4] = *(const float4*)&W1s[c*128 + wo + q*4];  // uniform b128
        #pragma unroll
        for (int i = 0; i < 32; ++i) acc1[i] += a * wv[i];
    }
    __syncthreads();                     // LT/W1s dead
    // bn1+relu -> Z; stage W2s
    #pragma unroll
    for (int i = 0; i < 32; ++i) {
        int o = wo + i;
        float v = fmaf(acc1[i] + c1[b*128 + o], sc[o], sc[128 + o]);
        Z[o*65 + lane] = fmaxf(v, 0.f);
    }
    for (int i = t; i < 2048; i += 256)
        *(float4*)&W2s[i*4] = *(const float4*)&W2T[i*4];
    __syncthreads();
    // gemm2: lane=row, wave owns 16 j
    const int wj = w * 16;
    float acc2[16] = {};
    #pragma unroll 2
    for (int o = 0; o < 128; ++o) {
        float zv = Z[o*65 + lane];
        float wv[16];
        #pragma unroll
        for (int q = 0; q < 4; ++q)
            *(float4*)&wv[q*4] = *(const float4*)&W2s[o*64 + wj + q*4];
        #pragma unroll
        for (int i = 0; i < 16; ++i) acc2[i] += zv * wv[i];
    }
    float s16[16], q16[16];
    #pragma unroll
    for (int i = 0; i < 16; ++i) {
        float v = acc2[i] + b2[wj + i];
        y2T[(size_t)(wj + i)*NROW + base + lane] = v;
        s16[i] = v; q16[i] = v*v;
    }
    // fused BN2 stats: LDS reduce (padded, conflict-free), then 2 wave-wide atomics per block
    __syncthreads();                     // Z/W2s reads done; buf reusable
    #pragma unroll
    for (int i = 0; i < 16; ++i) {
        SR[(wj + i)*68 + lane] = s16[i];
        QR[(wj + i)*68 + lane] = q16[i];
    }
    __syncthreads();
    if (t < 64) {
        float a = 0.f, bq = 0.f;
        #pragma unroll
        for (int l = 0; l < 64; l += 4) {
            float4 v = *(const float4*)&SR[t*68 + l];
            float4 u = *(const float4*)&QR[t*68 + l];
            a  += v.x + v.y + v.z + v.w;
            bq += u.x + u.y + u.z + u.w;
        }
        atomicAdd(&st2[t], a);           // wave-wide: 64 lanes -> 64 consecutive addrs
        atomicAdd(&st2[64 + t], bq);
    }
}

__global__ void k_fin2(const float* __restrict__ st2, const float* __restrict__ g2,
                       const float* __restrict__ be2, float* __restrict__ sc2) {
    const int o = threadIdx.x;  // 64
    float mu = st2[o] * INV_BN;
    float var = st2[64 + o] * INV_BN - mu*mu;
    float s = g2[o] * rsqrtf(var + EPSF);
    sc2[o] = s; sc2[64 + o] = be2[o] - mu*s;
}

// ------------------------------------------------------------------ GEMM3: lane=row, wave=16 c, M in LDS; LDS out-transpose
// out[row][c] = sum_j relu(bn2(y2T[j][row]))*MT[b][j][c] + dv[b][c]
__global__ __launch_bounds__(256) void k_gemm3(const float* __restrict__ y2T,
        const float* __restrict__ MT, const float* __restrict__ dv,
        const float* __restrict__ sc2, float* __restrict__ out) {
    __shared__ __align__(16) float Ml[64*64];        // 16 KB
    __shared__ float Ot[64*65];                      // 16.6 KB
    const int t = threadIdx.x;
    const int base = blockIdx.x * 64;                // 1024 blocks
    const int b = blockIdx.x >> 8;
    for (int i = t; i < 1024; i += 256)
        *(float4*)&Ml[i*4] = *(const float4*)&MT[b*4096 + i*4];
    __syncthreads();
    const int lane = t & 63;
    const int wc = (t >> 6) * 16;
    const float* ap = y2T + base + lane;
    float acc[16] = {};
    #pragma unroll 4
    for (int j = 0; j < 64; ++j) {
        float v = ap[(size_t)j*NROW];
        v = fmaxf(fmaf(v, sc2[j], sc2[64 + j]), 0.f); // bn2 + relu
        float wv[16];
        #pragma unroll
        for (int q = 0; q < 4; ++q)
            *(float4*)&wv[q*4] = *(const float4*)&Ml[j*64 + wc + q*4];
        #pragma unroll
        for (int ci = 0; ci < 16; ++ci) acc[ci] += v * wv[ci];
    }
    #pragma unroll
    for (int ci = 0; ci < 16; ++ci)
        Ot[(wc + ci)*65 + lane] = acc[ci] + dv[b*64 + wc + ci];
    __syncthreads();
    for (int i = t; i < 4096; i += 256) {            // coalesced row-major store
        int r = i >> 6, c = i & 63;
        out[(base + r)*64 + c] = Ot[c*65 + r];
    }
}

// ------------------------------------------------------------------
extern "C" void kernel_launch(void* const* d_in, const int* in_sizes, int n_in,
                              void* d_out, int out_size, void* d_ws, size_t ws_size,
                              hipStream_t stream) {
    const float* lidar = (const float*)d_in[0];
    const float* img   = (const float*)d_in[1];
    const float* W1  = (const float*)d_in[2];
    const float* b1  = (const float*)d_in[3];
    const float* g1  = (const float*)d_in[4];
    const float* be1 = (const float*)d_in[5];
    const float* W2  = (const float*)d_in[6];
    const float* b2  = (const float*)d_in[7];
    const float* g2  = (const float*)d_in[8];
    const float* be2 = (const float*)d_in[9];
    const float* W3  = (const float*)d_in[10];
    const float* b3  = (const float*)d_in[11];

    float* ws   = (float*)d_ws;
    float* y2T  = ws;                    // 64*65536
    float* g    = y2T + 64*NROW;         // 256
    float* c1   = g    + 256;            // 512
    float* MT   = c1   + 512;            // 16384
    float* dv   = MT   + 16384;          // 256
    float* W1hT = dv   + 256;            // 8192
    float* W2T  = W1hT + 8192;           // 8192
    float* sc1  = W2T  + 8192;           // 256
    float* sc2  = sc1  + 256;            // 128
    float* G    = sc2  + 128;            // 16384
    float* S    = G    + 16384;          // 256
    float* st2  = S    + 256;            // 128   -- zeroed
    float* Gp   = st2  + 128;            // 1024*4096
    float* Sp   = Gp   + 1024*4096;      // 1024*64

    hipMemsetAsync(st2, 0, 128 * sizeof(float), stream);

    k_prep   <<<256,  1024, 0, stream>>>(img, W3, b3, g, MT, dv);
    k_wt     <<<1,    512,  0, stream>>>(W1, W2, b1, g, W1hT, W2T, c1);
    k_mom    <<<1024, 256,  0, stream>>>(lidar, Gp, Sp);
    k_mred   <<<65,   256,  0, stream>>>(Gp, Sp, G, S);
    k_stats1 <<<128,  256,  0, stream>>>(G, S, c1, W1hT, g1, be1, sc1);
    k_fused12<<<1024, 256,  0, stream>>>(lidar, W1hT, W2T, c1, sc1, b2, y2T, st2);
    k_fin2   <<<1,    64,   0, stream>>>(st2, g2, be2, sc2);
    k_gemm3  <<<1024, 256,  0, stream>>>(y2T, MT, dv, sc2, (float*)d_out);
}